// Round 8
// baseline (112.223 us; speedup 1.0000x reference)
//
#include <hip/hip_runtime.h>

// RoiPooling (crop_and_resize, bilinear): x (1,128,128,256) f32 NHWC,
// rois (4000,4) f32 [y1,x1,y2,x2] in [0,1] -> out (4000,7,7,256) f32.
//
// R8: exact-pixel counting sort + flat-partition pool.
// R7 showed balance is not the limiter; 784MB gathers at 12.9 TB/s are
// random 1KB L2 accesses with zero L1 capture. Sorting cells by corner
// pixel (y0,x0) makes consecutive cells share all 4 corner rows ->
// block-level gathers collapse to ~4KB distinct lines (L1 hits), L2
// stream becomes sequential. Sort: LDS histogram (16384 buckets, 64KB)
// -> padded global counters (~12 adds each) -> 1-block prefix ->
// LDS-ranked scatter. Pool: R7 flat partition (XCD j owns y0-major
// slab), 2 cells/wave, NT stores.

typedef float v4f __attribute__((ext_vector_type(4)));

constexpr int H = 128, W = 128, C = 256;
constexpr int PH = 7, PW = 7;
constexpr int NROI = 4000;
constexpr int NCELL = NROI * PH * PW;            // 196000
constexpr int NBUCK = H * W;                     // 16384 pixel buckets
constexpr int CSTRIDE = 16;                      // ints; 64B per counter
constexpr int NXCD = 8;
constexpr int M = NCELL / NXCD;                  // 24500 cells per XCD
constexpr int GROUPS = 256;                      // blocks per XCD
constexpr int P2_BLOCKS = NXCD * GROUPS;         // 2048
constexpr int BIN_BLOCKS = (NCELL + 255) / 256;  // 766
// ws: cnt | head | P | list
constexpr size_t WS_CNT  = (size_t)NBUCK * CSTRIDE;
constexpr size_t WS_INTS = 2 * WS_CNT + (NBUCK + 1) + NCELL;

__global__ __launch_bounds__(256) void zero_counts(int* p) {
    const int i = blockIdx.x * 256 + threadIdx.x;
    const int n = (int)(2 * WS_CNT);
    for (int j = i; j < n; j += 512 * 256) p[j] = 0;
}

__device__ __forceinline__ int cell_bucket(const float* __restrict__ rois, int cell) {
    const int r  = cell / (PH * PW);
    const int pq = cell - r * (PH * PW);
    const int iy = pq / PW;
    const int ix = pq - iy * PW;
    const float y1 = rois[r * 4 + 0];
    const float x1 = rois[r * 4 + 1];
    const float y2 = rois[r * 4 + 2];
    const float x2 = rois[r * 4 + 3];
    const float ys = y1 * (float)(H - 1) + (float)iy * ((y2 - y1) * (float)(H - 1) / (float)(PH - 1));
    const float xs = x1 * (float)(W - 1) + (float)ix * ((x2 - x1) * (float)(W - 1) / (float)(PW - 1));
    int y0 = (int)floorf(ys); y0 = min(max(y0, 0), H - 1);
    int x0 = (int)floorf(xs); x0 = min(max(x0, 0), W - 1);
    return (y0 << 7) | x0;
}

__global__ __launch_bounds__(256) void hist_cells(const float* __restrict__ rois,
                                                  int* __restrict__ cnt)
{
    __shared__ int lh[NBUCK];                    // 64KB
    for (int i = threadIdx.x; i < NBUCK; i += 256) lh[i] = 0;
    __syncthreads();
    const int cell = blockIdx.x * 256 + threadIdx.x;
    if (cell < NCELL) atomicAdd(&lh[cell_bucket(rois, cell)], 1);
    __syncthreads();
    for (int i = threadIdx.x; i < NBUCK; i += 256) {
        const int n = lh[i];
        if (n) atomicAdd(&cnt[i * CSTRIDE], n);
    }
}

__global__ __launch_bounds__(1024) void prefix_sum(const int* __restrict__ cnt,
                                                   int* __restrict__ P)
{
    __shared__ int tsum[1024];
    const int t = threadIdx.x;
    int vals[16];
    int s = 0;
#pragma unroll
    for (int i = 0; i < 16; ++i) { vals[i] = cnt[(t * 16 + i) * CSTRIDE]; s += vals[i]; }
    tsum[t] = s;
    __syncthreads();
    for (int off = 1; off < 1024; off <<= 1) {
        const int v = (t >= off) ? tsum[t - off] : 0;
        __syncthreads();
        tsum[t] += v;
        __syncthreads();
    }
    int base = (t == 0) ? 0 : tsum[t - 1];
#pragma unroll
    for (int i = 0; i < 16; ++i) { P[t * 16 + i] = base; base += vals[i]; }
    if (t == 1023) P[NBUCK] = base;
}

__global__ __launch_bounds__(256) void scatter_cells(const float* __restrict__ rois,
                                                     const int* __restrict__ P,
                                                     int* __restrict__ head,
                                                     int* __restrict__ list)
{
    __shared__ int lh[NBUCK];                    // counts, then bases
    for (int i = threadIdx.x; i < NBUCK; i += 256) lh[i] = 0;
    __syncthreads();
    const int cell = blockIdx.x * 256 + threadIdx.x;
    const bool active = cell < NCELL;
    int bucket = 0, rank = 0;
    if (active) {
        bucket = cell_bucket(rois, cell);
        rank = atomicAdd(&lh[bucket], 1);
    }
    __syncthreads();
    for (int i = threadIdx.x; i < NBUCK; i += 256) {
        const int n = lh[i];
        if (n) lh[i] = P[i] + atomicAdd(&head[i * CSTRIDE], n);
    }
    __syncthreads();
    if (active) list[lh[bucket] + rank] = cell;
}

__device__ __forceinline__ void cell_geom(const float* __restrict__ rois, int cell,
                                          unsigned& b00, unsigned& b01,
                                          unsigned& b10, unsigned& b11,
                                          float& wy, float& wx, bool& valid)
{
    const int r  = cell / (PH * PW);
    const int pq = cell - r * (PH * PW);
    const int iy = pq / PW;
    const int ix = pq - iy * PW;

    const float y1 = rois[r * 4 + 0];
    const float x1 = rois[r * 4 + 1];
    const float y2 = rois[r * 4 + 2];
    const float x2 = rois[r * 4 + 3];

    // Match reference order exactly.
    const float ys = y1 * (float)(H - 1) + (float)iy * ((y2 - y1) * (float)(H - 1) / (float)(PH - 1));
    const float xs = x1 * (float)(W - 1) + (float)ix * ((x2 - x1) * (float)(W - 1) / (float)(PW - 1));

    const float y0f = floorf(ys);
    const float x0f = floorf(xs);
    wy = ys - y0f;
    wx = xs - x0f;

    int y0  = (int)y0f; y0  = min(max(y0, 0), H - 1);
    int y1i = min(y0 + 1, H - 1);
    int x0  = (int)x0f; x0  = min(max(x0, 0), W - 1);
    int x1i = min(x0 + 1, W - 1);

    valid = (ys >= 0.0f) & (ys <= (float)(H - 1)) &
            (xs >= 0.0f) & (xs <= (float)(W - 1));

    b00 = ((unsigned)(y0  * W + x0 )) * C;
    b01 = ((unsigned)(y0  * W + x1i)) * C;
    b10 = ((unsigned)(y1i * W + x0 )) * C;
    b11 = ((unsigned)(y1i * W + x1i)) * C;
}

__global__ __launch_bounds__(256) void roi_pool_flat(
    const float* __restrict__ x, const float* __restrict__ rois,
    float* __restrict__ out, const int* __restrict__ list)
{
    const int xcd = blockIdx.x & (NXCD - 1);   // heuristic: == XCD id
    const int grp = blockIdx.x >> 3;
    const int wave = threadIdx.x >> 6;
    const int lane = threadIdx.x & 63;
    const unsigned c4 = (unsigned)lane * 4u;
    const int gbase = xcd * M;

    for (int c = grp; c * 8 < M; c += GROUPS) {
        const int local0 = c * 8 + wave * 2;
        int cells[2]; bool live[2], validv[2];
        float wxv[2], wyv[2];
        v4f a[2], b[2], cc[2], d[2];
#pragma unroll
        for (int k = 0; k < 2; ++k) {
            const int local = local0 + k;
            live[k] = (local < M);
            const int g = gbase + min(local, M - 1);
            const int cell = list[g];
            cells[k] = cell;
            unsigned b00, b01, b10, b11;
            cell_geom(rois, cell, b00, b01, b10, b11, wyv[k], wxv[k], validv[k]);
            if (live[k]) {
                a[k]  = *(const v4f*)(x + b00 + c4);
                b[k]  = *(const v4f*)(x + b01 + c4);
                cc[k] = *(const v4f*)(x + b10 + c4);
                d[k]  = *(const v4f*)(x + b11 + c4);
            }
        }
#pragma unroll
        for (int k = 0; k < 2; ++k) {
            if (!live[k]) continue;
            const float wx = wxv[k], wy = wyv[k];
            const v4f top = a[k]  * (1.0f - wx) + b[k] * wx;
            const v4f bot = cc[k] * (1.0f - wx) + d[k] * wx;
            v4f res = top * (1.0f - wy) + bot * wy;
            if (!validv[k]) res = (v4f)0.0f;
            v4f* o = (v4f*)(out + (unsigned)cells[k] * C + c4);
            __builtin_nontemporal_store(res, o);
        }
    }
}

// Fallback (ws too small): direct kernel.
__global__ __launch_bounds__(256) void roi_pool_plain(
    const float* __restrict__ x, const float* __restrict__ rois,
    float* __restrict__ out)
{
    const int wave = threadIdx.x >> 6;
    const int lane = threadIdx.x & 63;
    const int cell0 = (blockIdx.x * 4 + wave) * 2;
    const unsigned c4 = (unsigned)lane * 4u;

    v4f a[2], b[2], c[2], d[2];
    float wxv[2], wyv[2]; bool validv[2];
#pragma unroll
    for (int k = 0; k < 2; ++k) {
        unsigned b00, b01, b10, b11;
        cell_geom(rois, cell0 + k, b00, b01, b10, b11, wyv[k], wxv[k], validv[k]);
        a[k] = *(const v4f*)(x + b00 + c4);
        b[k] = *(const v4f*)(x + b01 + c4);
        c[k] = *(const v4f*)(x + b10 + c4);
        d[k] = *(const v4f*)(x + b11 + c4);
    }
#pragma unroll
    for (int k = 0; k < 2; ++k) {
        const float wx = wxv[k], wy = wyv[k];
        const v4f top = a[k] * (1.0f - wx) + b[k] * wx;
        const v4f bot = c[k] * (1.0f - wx) + d[k] * wx;
        v4f res = top * (1.0f - wy) + bot * wy;
        if (!validv[k]) res = (v4f)0.0f;
        v4f* o = (v4f*)(out + (unsigned)(cell0 + k) * C + c4);
        __builtin_nontemporal_store(res, o);
    }
}

extern "C" void kernel_launch(void* const* d_in, const int* in_sizes, int n_in,
                              void* d_out, int out_size, void* d_ws, size_t ws_size,
                              hipStream_t stream)
{
    const float* x    = (const float*)d_in[0];
    const float* rois = (const float*)d_in[1];
    float* out = (float*)d_out;

    if (ws_size >= WS_INTS * sizeof(int)) {
        int* cnt  = (int*)d_ws;
        int* head = cnt + WS_CNT;
        int* P    = head + WS_CNT;
        int* list = P + (NBUCK + 1);
        zero_counts<<<512, 256, 0, stream>>>(cnt);
        hist_cells<<<BIN_BLOCKS, 256, 0, stream>>>(rois, cnt);
        prefix_sum<<<1, 1024, 0, stream>>>(cnt, P);
        scatter_cells<<<BIN_BLOCKS, 256, 0, stream>>>(rois, P, head, list);
        roi_pool_flat<<<P2_BLOCKS, 256, 0, stream>>>(x, rois, out, list);
    } else {
        roi_pool_plain<<<NCELL / 8, 256, 0, stream>>>(x, rois, out);
    }
}

// Round 9
// 66.403 us; speedup vs baseline: 1.6900x; 1.6900x over previous
//
#include <hip/hip_runtime.h>

// RoiPooling (crop_and_resize, bilinear): x (1,128,128,256) f32 NHWC,
// rois (4000,4) f32 [y1,x1,y2,x2] in [0,1] -> out (4000,7,7,256) f32.
//
// R9: row-sort (y0, 128 buckets) + flat-partition pool.
// R8's exact-pixel sort won nothing net: 16k-bucket LDS passes + ~196k
// global merge atomics. Row-sort is enough: flat slab per XCD processed
// as a moving ~2-row (~300KB) window -> reuse distance ~2us -> L2-hit
// gathers. Sort = R5's cheap structure: 128 blocks, 128-int LDS hist,
// merge = 128 atomics/line (chain 128), 1-block prefix, ranked scatter.

typedef float v4f __attribute__((ext_vector_type(4)));

constexpr int H = 128, W = 128, C = 256;
constexpr int PH = 7, PW = 7;
constexpr int NROI = 4000;
constexpr int NCELL = NROI * PH * PW;            // 196000
constexpr int RBUCK = 128;                       // one bucket per y0 row
constexpr int CSTRIDE = 32;                      // ints; 128B per counter
constexpr int BIN_BLOCKS = 128;
constexpr int CPB = (NCELL + BIN_BLOCKS - 1) / BIN_BLOCKS;  // 1532
constexpr int NXCD = 8;
constexpr int M = NCELL / NXCD;                  // 24500 cells per XCD
constexpr int GROUPS = 256;                      // blocks per XCD
constexpr int P2_BLOCKS = NXCD * GROUPS;         // 2048
constexpr size_t WS_CNT  = (size_t)RBUCK * CSTRIDE;
constexpr size_t WS_INTS = 2 * WS_CNT + (RBUCK + 1) + NCELL;

__global__ __launch_bounds__(256) void zero_counts(int* p) {
    const int n = (int)(2 * WS_CNT);             // cnt + head
    for (int j = threadIdx.x; j < n; j += 256) p[j] = 0;
}

__device__ __forceinline__ int cell_ybucket(const float* __restrict__ rois, int cell) {
    const int r  = cell / (PH * PW);
    const int pq = cell - r * (PH * PW);
    const int iy = pq / PW;
    const float y1 = rois[r * 4 + 0];
    const float y2 = rois[r * 4 + 2];
    const float ys = y1 * (float)(H - 1) + (float)iy * ((y2 - y1) * (float)(H - 1) / (float)(PH - 1));
    int y0 = (int)floorf(ys);
    return min(max(y0, 0), H - 1);
}

__global__ __launch_bounds__(256) void hist_cells(const float* __restrict__ rois,
                                                  int* __restrict__ cnt)
{
    __shared__ int lh[RBUCK];
    for (int i = threadIdx.x; i < RBUCK; i += 256) lh[i] = 0;
    __syncthreads();
    const int c0 = blockIdx.x * CPB;
    const int c1 = min(c0 + CPB, NCELL);
    for (int cell = c0 + threadIdx.x; cell < c1; cell += 256)
        atomicAdd(&lh[cell_ybucket(rois, cell)], 1);
    __syncthreads();
    for (int i = threadIdx.x; i < RBUCK; i += 256) {
        const int n = lh[i];
        if (n) atomicAdd(&cnt[i * CSTRIDE], n);
    }
}

__global__ __launch_bounds__(128) void prefix_sum(const int* __restrict__ cnt,
                                                  int* __restrict__ P)
{
    __shared__ int s[RBUCK];
    const int t = threadIdx.x;
    s[t] = cnt[t * CSTRIDE];
    __syncthreads();
    for (int off = 1; off < RBUCK; off <<= 1) {
        const int v = (t >= off) ? s[t - off] : 0;
        __syncthreads();
        s[t] += v;
        __syncthreads();
    }
    P[t + 1] = s[t];
    if (t == 0) P[0] = 0;
}

__global__ __launch_bounds__(256) void scatter_cells(const float* __restrict__ rois,
                                                     const int* __restrict__ P,
                                                     int* __restrict__ head,
                                                     int* __restrict__ list)
{
    __shared__ int lcnt[RBUCK];
    __shared__ int gbase[RBUCK];
    for (int i = threadIdx.x; i < RBUCK; i += 256) lcnt[i] = 0;
    __syncthreads();
    const int c0 = blockIdx.x * CPB;
    const int c1 = min(c0 + CPB, NCELL);
    int myb[6], myr[6];
    {
        int j = 0;
        for (int cell = c0 + threadIdx.x; cell < c1; cell += 256, ++j) {
            const int b = cell_ybucket(rois, cell);
            myb[j] = b;
            myr[j] = atomicAdd(&lcnt[b], 1);
        }
    }
    __syncthreads();
    for (int i = threadIdx.x; i < RBUCK; i += 256) {
        const int n = lcnt[i];
        gbase[i] = n ? P[i] + atomicAdd(&head[i * CSTRIDE], n) : 0;
    }
    __syncthreads();
    {
        int j = 0;
        for (int cell = c0 + threadIdx.x; cell < c1; cell += 256, ++j)
            list[gbase[myb[j]] + myr[j]] = cell;
    }
}

__device__ __forceinline__ void cell_geom(const float* __restrict__ rois, int cell,
                                          unsigned& b00, unsigned& b01,
                                          unsigned& b10, unsigned& b11,
                                          float& wy, float& wx, bool& valid)
{
    const int r  = cell / (PH * PW);
    const int pq = cell - r * (PH * PW);
    const int iy = pq / PW;
    const int ix = pq - iy * PW;

    const float y1 = rois[r * 4 + 0];
    const float x1 = rois[r * 4 + 1];
    const float y2 = rois[r * 4 + 2];
    const float x2 = rois[r * 4 + 3];

    // Match reference order exactly.
    const float ys = y1 * (float)(H - 1) + (float)iy * ((y2 - y1) * (float)(H - 1) / (float)(PH - 1));
    const float xs = x1 * (float)(W - 1) + (float)ix * ((x2 - x1) * (float)(W - 1) / (float)(PW - 1));

    const float y0f = floorf(ys);
    const float x0f = floorf(xs);
    wy = ys - y0f;
    wx = xs - x0f;

    int y0  = (int)y0f; y0  = min(max(y0, 0), H - 1);
    int y1i = min(y0 + 1, H - 1);
    int x0  = (int)x0f; x0  = min(max(x0, 0), W - 1);
    int x1i = min(x0 + 1, W - 1);

    valid = (ys >= 0.0f) & (ys <= (float)(H - 1)) &
            (xs >= 0.0f) & (xs <= (float)(W - 1));

    b00 = ((unsigned)(y0  * W + x0 )) * C;
    b01 = ((unsigned)(y0  * W + x1i)) * C;
    b10 = ((unsigned)(y1i * W + x0 )) * C;
    b11 = ((unsigned)(y1i * W + x1i)) * C;
}

__global__ __launch_bounds__(256) void roi_pool_flat(
    const float* __restrict__ x, const float* __restrict__ rois,
    float* __restrict__ out, const int* __restrict__ list)
{
    const int xcd = blockIdx.x & (NXCD - 1);   // heuristic: == XCD id
    const int grp = blockIdx.x >> 3;
    const int wave = threadIdx.x >> 6;
    const int lane = threadIdx.x & 63;
    const unsigned c4 = (unsigned)lane * 4u;
    const int gbase = xcd * M;

    for (int c = grp; c * 8 < M; c += GROUPS) {
        const int local0 = c * 8 + wave * 2;
        int cells[2]; bool live[2], validv[2];
        float wxv[2], wyv[2];
        v4f a[2], b[2], cc[2], d[2];
#pragma unroll
        for (int k = 0; k < 2; ++k) {
            const int local = local0 + k;
            live[k] = (local < M);
            const int g = gbase + min(local, M - 1);
            const int cell = list[g];
            cells[k] = cell;
            unsigned b00, b01, b10, b11;
            cell_geom(rois, cell, b00, b01, b10, b11, wyv[k], wxv[k], validv[k]);
            if (live[k]) {
                a[k]  = *(const v4f*)(x + b00 + c4);
                b[k]  = *(const v4f*)(x + b01 + c4);
                cc[k] = *(const v4f*)(x + b10 + c4);
                d[k]  = *(const v4f*)(x + b11 + c4);
            }
        }
#pragma unroll
        for (int k = 0; k < 2; ++k) {
            if (!live[k]) continue;
            const float wx = wxv[k], wy = wyv[k];
            const v4f top = a[k]  * (1.0f - wx) + b[k] * wx;
            const v4f bot = cc[k] * (1.0f - wx) + d[k] * wx;
            v4f res = top * (1.0f - wy) + bot * wy;
            if (!validv[k]) res = (v4f)0.0f;
            v4f* o = (v4f*)(out + (unsigned)cells[k] * C + c4);
            __builtin_nontemporal_store(res, o);
        }
    }
}

// Fallback (ws too small): direct kernel.
__global__ __launch_bounds__(256) void roi_pool_plain(
    const float* __restrict__ x, const float* __restrict__ rois,
    float* __restrict__ out)
{
    const int wave = threadIdx.x >> 6;
    const int lane = threadIdx.x & 63;
    const int cell0 = (blockIdx.x * 4 + wave) * 2;
    const unsigned c4 = (unsigned)lane * 4u;

    v4f a[2], b[2], c[2], d[2];
    float wxv[2], wyv[2]; bool validv[2];
#pragma unroll
    for (int k = 0; k < 2; ++k) {
        unsigned b00, b01, b10, b11;
        cell_geom(rois, cell0 + k, b00, b01, b10, b11, wyv[k], wxv[k], validv[k]);
        a[k] = *(const v4f*)(x + b00 + c4);
        b[k] = *(const v4f*)(x + b01 + c4);
        c[k] = *(const v4f*)(x + b10 + c4);
        d[k] = *(const v4f*)(x + b11 + c4);
    }
#pragma unroll
    for (int k = 0; k < 2; ++k) {
        const float wx = wxv[k], wy = wyv[k];
        const v4f top = a[k] * (1.0f - wx) + b[k] * wx;
        const v4f bot = c[k] * (1.0f - wx) + d[k] * wx;
        v4f res = top * (1.0f - wy) + bot * wy;
        if (!validv[k]) res = (v4f)0.0f;
        v4f* o = (v4f*)(out + (unsigned)(cell0 + k) * C + c4);
        __builtin_nontemporal_store(res, o);
    }
}

extern "C" void kernel_launch(void* const* d_in, const int* in_sizes, int n_in,
                              void* d_out, int out_size, void* d_ws, size_t ws_size,
                              hipStream_t stream)
{
    const float* x    = (const float*)d_in[0];
    const float* rois = (const float*)d_in[1];
    float* out = (float*)d_out;

    if (ws_size >= WS_INTS * sizeof(int)) {
        int* cnt  = (int*)d_ws;
        int* head = cnt + WS_CNT;
        int* P    = head + WS_CNT;
        int* list = P + (RBUCK + 1);
        zero_counts<<<1, 256, 0, stream>>>(cnt);
        hist_cells<<<BIN_BLOCKS, 256, 0, stream>>>(rois, cnt);
        prefix_sum<<<1, 128, 0, stream>>>(cnt, P);
        scatter_cells<<<BIN_BLOCKS, 256, 0, stream>>>(rois, P, head, list);
        roi_pool_flat<<<P2_BLOCKS, 256, 0, stream>>>(x, rois, out, list);
    } else {
        roi_pool_plain<<<NCELL / 8, 256, 0, stream>>>(x, rois, out);
    }
}